// Round 10
// baseline (288.568 us; speedup 1.0000x reference)
//
#include <hip/hip_runtime.h>
#include <hip/hip_bf16.h>

#define NB 32
#define NS 1024
#define ND 768
#define BS_TOT (NB * NS)  // 32768

// sim scale = 1 / (0.7 * sqrt(768))
#define SCALE 0.05154913f

// ---------------------------------------------------------------------------
// Linearized SupCon: exp(sim/N) = 1 + sim/N + O(1e-6 rel). The loss collapses
// to per-batch group sums g_P, batch sum G, per-anchor dots f_i.(G-g_P) and
// |f_i|^2, plus label-only counts. O(B*S*D), two feature passes, no Gram.
// Verified rounds 7-9: absmax 0.0 vs np reference.
// ---------------------------------------------------------------------------

// ---------------- Kernel 1: per-anchor metadata (labels only) --------------
// Handles labels as int32 or raw int64 (odd 32-bit words all zero -> int64).
// nlater via parallel histogram scan: rank_i = #same-label before i;
// nlat_i = gs - 1 - rank_i.
__global__ __launch_bounds__(256) void meta_kernel(
    const int* __restrict__ lr, float* __restrict__ invN,
    float* __restrict__ invGS, float* __restrict__ numneg,
    float* __restrict__ nlat, int* __restrict__ labI,
    float* __restrict__ cntG, float* __restrict__ gnorm,
    float* __restrict__ out) {
  __shared__ int labs[NS];        // 4 KB
  __shared__ int hist[256][17];   // 17 KB (pad 17 -> conflict-free columns)
  __shared__ int cnt[16];
  __shared__ int is64;
  int b = blockIdx.x, t = threadIdx.x;
  if (t == 0) is64 = 1;
  if (t < 16) cnt[t] = 0;
  __syncthreads();
  int bad = 0;
  for (int k = t; k < 1024; k += 256) bad |= lr[2 * k + 1];
  if (bad) atomicAnd(&is64, 0);
  __syncthreads();
  const bool i64 = (is64 != 0);
  for (int i = t; i < NS; i += 256) {
    int gi = b * NS + i;
    int lab = (i64 ? lr[2 * gi] : lr[gi]) & 15;
    labs[i] = lab;
    atomicAdd(&cnt[lab], 1);
  }
#pragma unroll
  for (int L = 0; L < 16; ++L) hist[t][L] = 0;
  __syncthreads();
  int lab4[4];
#pragma unroll
  for (int e = 0; e < 4; ++e) {
    lab4[e] = labs[t * 4 + e];
    hist[t][lab4[e]]++;
  }
  __syncthreads();
#pragma unroll
  for (int off = 1; off < 256; off <<= 1) {
    int tmp[16];
#pragma unroll
    for (int L = 0; L < 16; ++L) tmp[L] = (t >= off) ? hist[t - off][L] : 0;
    __syncthreads();
#pragma unroll
    for (int L = 0; L < 16; ++L) hist[t][L] += tmp[L];
    __syncthreads();
  }
#pragma unroll
  for (int e = 0; e < 4; ++e) {
    int i = t * 4 + e;
    int gi = b * NS + i;
    int lab = lab4[e];
    int gs = cnt[lab];
    int nn = NS - gs;
    int later_own = 0;
#pragma unroll
    for (int e2 = 0; e2 < 4; ++e2)
      if (e2 > e && lab4[e2] == lab) later_own++;
    int rank = hist[t][lab] - 1 - later_own;
    invN[gi] = nn > 0 ? 1.0f / (float)nn : 0.0f;
    invGS[gi] = 1.0f / (float)gs;
    numneg[gi] = (float)nn;
    labI[gi] = lab;
    nlat[gi] = (float)(gs - 1 - rank);
  }
  if (t < 16) {
    cntG[b * 16 + t] = (float)cnt[t];
    gnorm[b * 16 + t] = 0.0f;  // ws is poisoned; zero before greduce atomics
  }
  if (b == 0 && t == 0) out[0] = 0.0f;
}

// ---------------- Kernel 2: partial group sums (round-10 rewrite) ----------
// Grid 512 = 32 batches x 16 chunks of 64 rows (2 blocks/CU, 8 waves/CU).
// float4 loads (i = k*256+t enumerates 64 rows x 192 float4-chunks,
// lane-consecutive -> 1 KB coalesced per instruction). Accumulation via
// ds_add_f32 atomics into an SoA LDS layout acc[4 planes][16 labels][192]:
// one LDS op per element (vs read+add+write), and within one atomic
// instruction lanes hit consecutive 4B addresses in a plane -> 2 lanes/bank
// = conflict-free (m136). Atomics make cross-wave same-label adds race-free.
// Writeout converts to standard [16][768] AoS for greduce.
__global__ __launch_bounds__(256) void gsum_kernel(
    const float* __restrict__ feat, const int* __restrict__ labI,
    float* __restrict__ gsumP) {
  const int b = blockIdx.x >> 4, rc = blockIdx.x & 15;
  __shared__ float acc[4][16 * 192];  // 48 KB, SoA planes (dim%4)
  __shared__ int labs[64];
  const int t = threadIdx.x;
  for (int i = t; i < 4 * 16 * 192; i += 256) (&acc[0][0])[i] = 0.0f;
  if (t < 64) labs[t] = labI[b * NS + rc * 64 + t];
  __syncthreads();
  const float* fp = feat + (size_t)(b * NS + rc * 64) * ND;
#pragma unroll 4
  for (int k = 0; k < 48; ++k) {
    int i = k * 256 + t;        // 0..12287 = 64 rows x 192 chunks
    int row = i / 192, ch = i - row * 192;
    float4 v = *(const float4*)(fp + (size_t)row * ND + ch * 4);
    int o = labs[row] * 192 + ch;
    atomicAdd(&acc[0][o], v.x);
    atomicAdd(&acc[1][o], v.y);
    atomicAdd(&acc[2][o], v.z);
    atomicAdd(&acc[3][o], v.w);
  }
  __syncthreads();
  float* o = gsumP + (size_t)(b * 16 + rc) * 16 * ND;
  for (int i = t; i < 16 * ND; i += 256) {
    int lab = i / ND;
    int d = i - lab * ND;
    o[i] = acc[d & 3][lab * 192 + (d >> 2)];
  }
}

// ---------------- Kernel 3: reduce partials, build dG = G - g_P, ||g_P||^2 -
__global__ __launch_bounds__(256) void greduce_kernel(
    const float* __restrict__ gsumP, float* __restrict__ dG,
    float* __restrict__ gnorm) {
  const int b = blockIdx.x / 3, ck = blockIdx.x % 3;
  const int d = ck * 256 + threadIdx.x;
  float g[16];
#pragma unroll
  for (int gi = 0; gi < 16; ++gi) g[gi] = 0.0f;
  for (int rc = 0; rc < 16; ++rc) {
    const float* p = gsumP + (size_t)(b * 16 + rc) * 16 * ND + d;
#pragma unroll
    for (int gi = 0; gi < 16; ++gi) g[gi] += p[gi * ND];
  }
  float G = 0.0f;
#pragma unroll
  for (int gi = 0; gi < 16; ++gi) G += g[gi];
#pragma unroll
  for (int gi = 0; gi < 16; ++gi)
    dG[(size_t)(b * 16 + gi) * ND + d] = G - g[gi];
#pragma unroll
  for (int gi = 0; gi < 16; ++gi) {
    float v = g[gi] * g[gi];
#pragma unroll
    for (int m = 1; m < 64; m <<= 1) v += __shfl_xor(v, m);
    if ((threadIdx.x & 63) == 0) atomicAdd(&gnorm[b * 16 + gi], v);
  }
}

// ---------------- Kernel 4: per-anchor dots -> per-anchor contrib ----------
// dG[16][768] staged in LDS once per block (48 KB); grid 512 = 32 batches x
// 16 chunks of 64 anchors (2 blocks/CU); 4 rows in flight per wave (12
// outstanding float4 pairs); per-anchor stores, zero atomics.
__global__ __launch_bounds__(256) void anchor_kernel(
    const float* __restrict__ feat, const int* __restrict__ labI,
    const float* __restrict__ dG, const float* __restrict__ invN,
    const float* __restrict__ invGS, const float* __restrict__ numneg,
    const float* __restrict__ nlat, float* __restrict__ contrib) {
  const int b = blockIdx.x >> 4, rc = blockIdx.x & 15;
  __shared__ float gsh[16 * ND];  // 48 KB
  __shared__ int labs[64];
  const int t = threadIdx.x;
  const float4* src = (const float4*)(dG + (size_t)b * 16 * ND);
  float4* dst = (float4*)gsh;
  for (int i = t; i < 16 * ND / 4; i += 256) dst[i] = src[i];
  if (t < 64) labs[t] = labI[b * NS + rc * 64 + t];
  __syncthreads();
  const int w = t >> 6, l = t & 63;
  for (int r0 = 0; r0 < 16; r0 += 4) {
    const int ab = b * NS + rc * 64 + w * 16 + r0;  // 4 consecutive anchors
    const float* f0 = feat + (size_t)ab * ND;
    float d1[4] = {0, 0, 0, 0}, sq[4] = {0, 0, 0, 0};
#pragma unroll
    for (int c = 0; c < 3; ++c) {
#pragma unroll
      for (int u = 0; u < 4; ++u) {
        float4 fa = *(const float4*)(f0 + (size_t)u * ND + l * 4 + 256 * c);
        float4 ga = *(const float4*)(gsh + labs[w * 16 + r0 + u] * ND +
                                     l * 4 + 256 * c);
        d1[u] += fa.x * ga.x + fa.y * ga.y + fa.z * ga.z + fa.w * ga.w;
        sq[u] += fa.x * fa.x + fa.y * fa.y + fa.z * fa.z + fa.w * fa.w;
      }
    }
#pragma unroll
    for (int m = 1; m < 64; m <<= 1) {
#pragma unroll
      for (int u = 0; u < 4; ++u) {
        d1[u] += __shfl_xor(d1[u], m);
        sq[u] += __shfl_xor(sq[u], m);
      }
    }
    if (l < 4) {
      int a = ab + l;
      float d1s = (l == 0) ? d1[0] : (l == 1) ? d1[1] : (l == 2) ? d1[2]
                                                                 : d1[3];
      float sqs = (l == 0) ? sq[0] : (l == 1) ? sq[1] : (l == 2) ? sq[2]
                                                                 : sq[3];
      float N = numneg[a];
      float v = 0.0f;
      if (N > 0.0f) {
        float neg = N + d1s * SCALE * invN[a];  // linearized neg_logits
        v = (nlat[a] * __logf(neg) + 0.5f * SCALE * sqs) * invGS[a];
      }
      contrib[a] = v;
    }
  }
}

// ---------------- Kernel 5: reduce per-anchor contribs (32 atomics) --------
__global__ __launch_bounds__(256) void creduce_kernel(
    const float* __restrict__ contrib, float* __restrict__ out) {
  const int base = blockIdx.x * 1024 + threadIdx.x;
  float s = contrib[base] + contrib[base + 256] + contrib[base + 512] +
            contrib[base + 768];
#pragma unroll
  for (int m = 1; m < 64; m <<= 1) s += __shfl_xor(s, m);
  __shared__ float ws[4];
  if ((threadIdx.x & 63) == 0) ws[threadIdx.x >> 6] = s;
  __syncthreads();
  if (threadIdx.x == 0)
    atomicAdd(out, (ws[0] + ws[1] + ws[2] + ws[3]) * (1.0f / NS));
}

// ---------------- Kernel 6: per-group -||g_P||^2 terms ---------------------
__global__ void group_kernel(const float* __restrict__ gnorm,
                             const float* __restrict__ cntG,
                             float* __restrict__ out) {
  const int i = threadIdx.x;  // 512 = 32 batches x 16 groups
  float c = cntG[i];
  float v = 0.0f;
  if (c > 0.0f && c < (float)NS)  // group exists and has negatives
    v = -0.5f * SCALE * gnorm[i] / c;
#pragma unroll
  for (int m = 1; m < 64; m <<= 1) v += __shfl_xor(v, m);
  __shared__ float ws[8];
  if ((threadIdx.x & 63) == 0) ws[threadIdx.x >> 6] = v;
  __syncthreads();
  if (threadIdx.x == 0) {
    float s = 0.0f;
#pragma unroll
    for (int k = 0; k < 8; ++k) s += ws[k];
    atomicAdd(out, s * (1.0f / NS));
  }
}

extern "C" void kernel_launch(void* const* d_in, const int* in_sizes, int n_in,
                              void* d_out, int out_size, void* d_ws,
                              size_t ws_size, hipStream_t stream) {
  (void)in_sizes;
  (void)n_in;
  (void)out_size;
  (void)ws_size;
  const float* feat = (const float*)d_in[0];
  const int* labels = (const int*)d_in[1];
  float* out = (float*)d_out;

  char* w = (char*)d_ws;
  float* gsumP = (float*)w;  // [32][16][16][768] = 25.2 MB
  size_t off = (size_t)NB * 16 * 16 * ND * 4;
  float* dG = (float*)(w + off);  // [32][16][768] = 1.6 MB
  off += (size_t)NB * 16 * ND * 4;
  float* invN = (float*)(w + off);
  off += (size_t)BS_TOT * 4;
  float* invGS = (float*)(w + off);
  off += (size_t)BS_TOT * 4;
  float* numneg = (float*)(w + off);
  off += (size_t)BS_TOT * 4;
  float* nlat = (float*)(w + off);
  off += (size_t)BS_TOT * 4;
  int* labI = (int*)(w + off);
  off += (size_t)BS_TOT * 4;
  float* contrib = (float*)(w + off);
  off += (size_t)BS_TOT * 4;
  float* cntG = (float*)(w + off);
  off += (size_t)NB * 16 * 4;
  float* gnorm = (float*)(w + off);
  off += (size_t)NB * 16 * 4;
  // total ws usage ~28 MB

  meta_kernel<<<NB, 256, 0, stream>>>(labels, invN, invGS, numneg, nlat, labI,
                                      cntG, gnorm, out);
  gsum_kernel<<<NB * 16, 256, 0, stream>>>(feat, labI, gsumP);
  greduce_kernel<<<NB * 3, 256, 0, stream>>>(gsumP, dG, gnorm);
  anchor_kernel<<<NB * 16, 256, 0, stream>>>(feat, labI, dG, invN, invGS,
                                             numneg, nlat, contrib);
  creduce_kernel<<<BS_TOT / 1024, 256, 0, stream>>>(contrib, out);
  group_kernel<<<1, 512, 0, stream>>>(gnorm, cntG, out);
}